// Round 1
// baseline (165.840 us; speedup 1.0000x reference)
//
#include <hip/hip_runtime.h>

// RandomForest inference: 131072 samples, 64 features, 64 complete binary
// trees of depth 12, 8-class majority vote (smallest-class tie-break).

constexpr int kSamples  = 131072;
constexpr int kFeatures = 64;
constexpr int kTrees    = 64;
constexpr int kDepth    = 12;
constexpr int kInternal = (1 << kDepth) - 1;   // 4095
constexpr int kLeaves   = 1 << kDepth;         // 4096
constexpr int kClasses  = 8;
constexpr int TPB       = 256;
constexpr int ILP       = 8;                   // independent tree chains per thread

struct Node { float thr; int feat; };          // 8 B, one dwordx2 per visit

// Pack (features, thresholds) into [tree][4096] Node array in workspace.
// Stride 4096 (not 4095) so tree base is (t << 12) — shift, no mul.
__global__ __launch_bounds__(TPB) void pack_nodes_kernel(
    const int* __restrict__ features, const float* __restrict__ thresholds,
    Node* __restrict__ packed)
{
    int i = blockIdx.x * TPB + threadIdx.x;
    if (i >= kTrees * kInternal) return;
    unsigned t = (unsigned)i / (unsigned)kInternal;
    unsigned n = (unsigned)i - t * (unsigned)kInternal;
    Node nd;
    nd.thr  = thresholds[i];
    nd.feat = features[i];
    packed[(t << kDepth) + n] = nd;
}

template <bool PACKED>
__global__ __launch_bounds__(TPB) void forest_kernel(
    const float* __restrict__ X,
    const Node* __restrict__ nodes,        // [kTrees][4096] when PACKED
    const int* __restrict__ features,      // [kTrees][4095] when !PACKED
    const float* __restrict__ thresholds,  // [kTrees][4095] when !PACKED
    const int* __restrict__ leaf_values,   // [kTrees][4096]
    int* __restrict__ out)
{
    // X rows for this block's 256 samples. 256*64*4 B = 64 KiB exactly.
    // Gather bank = (tid*64 + f) % 32 = f % 32 -> random f gives ~2-way
    // aliasing on average (2-way is free on gfx950).
    __shared__ float xs[TPB * kFeatures];

    const int tid  = threadIdx.x;
    const int base = blockIdx.x * TPB;

    // Coalesced cooperative stage of 256 contiguous X rows.
    for (int i = tid; i < TPB * kFeatures; i += TPB)
        xs[i] = X[base * kFeatures + i];
    __syncthreads();

    const float* __restrict__ myx = &xs[tid * kFeatures];

    // 8 vote counters packed into one u64 (counts <= 64 < 256).
    unsigned long long votes = 0ull;

    for (int t0 = 0; t0 < kTrees; t0 += ILP) {
        int n[ILP];
        #pragma unroll
        for (int j = 0; j < ILP; ++j) n[j] = 0;

        #pragma unroll
        for (int d = 0; d < kDepth; ++d) {
            #pragma unroll
            for (int j = 0; j < ILP; ++j) {   // 8 independent gather chains
                float thr; int f;
                if (PACKED) {
                    Node nd = nodes[((t0 + j) << kDepth) + n[j]];
                    thr = nd.thr; f = nd.feat;
                } else {
                    int idx = (t0 + j) * kInternal + n[j];
                    f   = features[idx];
                    thr = thresholds[idx];
                }
                n[j] = 2 * n[j] + 1 + (myx[f] > thr ? 1 : 0);
            }
        }

        #pragma unroll
        for (int j = 0; j < ILP; ++j) {
            int lv = leaf_values[((t0 + j) << kDepth) + (n[j] - kInternal)];
            votes += 1ull << (lv << 3);
        }
    }

    // argmax over 8 counters; strict '>' ascending keeps smallest class on tie
    int best = 0;
    int bc   = (int)(votes & 0xFFull);
    #pragma unroll
    for (int c = 1; c < kClasses; ++c) {
        int cnt = (int)((votes >> (c * 8)) & 0xFFull);
        if (cnt > bc) { bc = cnt; best = c; }
    }
    out[base + tid] = best;
}

extern "C" void kernel_launch(void* const* d_in, const int* in_sizes, int n_in,
                              void* d_out, int out_size, void* d_ws, size_t ws_size,
                              hipStream_t stream) {
    const float* X          = (const float*)d_in[0];
    const int*   features   = (const int*)d_in[1];
    const float* thresholds = (const float*)d_in[2];
    const int*   leaves     = (const int*)d_in[3];
    int*         out        = (int*)d_out;

    constexpr size_t kPackedBytes = (size_t)kTrees * kLeaves * sizeof(Node); // 2 MiB
    const int grid = kSamples / TPB; // 512

    if (ws_size >= kPackedBytes) {
        Node* packed = (Node*)d_ws;
        int pack_grid = (kTrees * kInternal + TPB - 1) / TPB;
        pack_nodes_kernel<<<pack_grid, TPB, 0, stream>>>(features, thresholds, packed);
        forest_kernel<true><<<grid, TPB, 0, stream>>>(X, packed, nullptr, nullptr,
                                                      leaves, out);
    } else {
        forest_kernel<false><<<grid, TPB, 0, stream>>>(X, nullptr, features, thresholds,
                                                       leaves, out);
    }
}